// Round 14
// baseline (340.363 us; speedup 1.0000x reference)
//
#include <hip/hip_runtime.h>
#include <math.h>

#define Nn 512
#define Mm 32000
#define Bb 64
#define Tt 256
#define NCONS 4     // consumer (recursion) blocks, 1024 threads / 16 waves each
#define NPROD 128   // producer (emission) blocks

typedef float v4f __attribute__((ext_vector_type(4)));
typedef float f4  __attribute__((ext_vector_type(4)));
typedef int   v4i __attribute__((ext_vector_type(4)));
typedef int   v8i __attribute__((ext_vector_type(8)));

// pack 4 f32 -> 4 OCP e4m3 bytes in an int
__device__ inline int pk4fp8(float a, float b, float c, float d) {
  int r = __builtin_amdgcn_cvt_pk_fp8_f32(a, b, 0, false);
  r = __builtin_amdgcn_cvt_pk_fp8_f32(c, d, r, true);
  return r;
}

// ---- colsum[k] = sum_j exp(trans[j][k]) ----
__global__ void k_colsum(const float* __restrict__ trans, float* __restrict__ colsum) {
  int tid = threadIdx.x;
  int j0 = blockIdx.x * 16;
  float a0 = 0.f, a1 = 0.f;
  for (int r = 0; r < 16; ++r) {
    a0 += __expf(trans[(j0 + r) * Nn + tid]);
    a1 += __expf(trans[(j0 + r) * Nn + 256 + tid]);
  }
  atomicAdd(&colsum[tid], a0);
  atomicAdd(&colsum[256 + tid], a1);
}

// ---- A_s[j][k] = 256*exp(trans[j][k])/colsum[k] as e4m3 ----
__global__ void k_writeA8(const float* __restrict__ trans, const float* __restrict__ colsum,
                          int* __restrict__ A8) {
  int d = blockIdx.x * 256 + threadIdx.x;
  int j = d >> 7, k0 = (d & 127) << 2;
  float v0 = 256.f * __expf(trans[j * Nn + k0 + 0]) / colsum[k0 + 0];
  float v1 = 256.f * __expf(trans[j * Nn + k0 + 1]) / colsum[k0 + 1];
  float v2 = 256.f * __expf(trans[j * Nn + k0 + 2]) / colsum[k0 + 2];
  float v3 = 256.f * __expf(trans[j * Nn + k0 + 3]) / colsum[k0 + 3];
  A8[d] = pk4fp8(v0, v1, v2, v3);
}

// ---- fused: blocks 0-3 recursion consumers (16 waves, 32 A-rows/wave), 4-131 producers ----
// waves_per_eu(4,4): pin EXACTLY 4 waves/SIMD -> firm 128-reg unified budget
// (r9's __launch_bounds__(1024,4) let the allocator chase 8 waves/EU -> 64-reg
// budget -> af spilled). "+a" launder (binding verified r13) puts af's 64 regs
// in the AGPR class; measured VGPR working set ~60 (r9) -> 124 <= 128 fits.
// r13 A/B proved 2-wave cruise is latency-bound, not A-traffic-bound: 4 waves/SIMD
// overlap each wave's ~1500cy serial phase with other waves' MFMA phases.
__global__ __attribute__((amdgpu_flat_work_group_size(1024, 1024), amdgpu_waves_per_eu(4, 4)))
void k_fused(
    const char* __restrict__ A8, const float* __restrict__ emis,
    const int* __restrict__ x, const float* __restrict__ prior,
    const int* __restrict__ Tlen, float* __restrict__ Pem2,
    int* __restrict__ progress, float* __restrict__ out)
{
  __shared__ __align__(16) char ybuf[2][16 * Nn];   // fp8 Y [c][k], XOR-swizzled; 16 KB
  __shared__ __align__(16) float Spart[2][16][20];  // [c][w] column-sum partials (padded)
  __shared__ __align__(16) float ss[1024];
  __shared__ __align__(16) f4 ss4[1024];
  const int tid = threadIdx.x;

  if (blockIdx.x >= NCONS) {
    // ================= producer: 4 emis rows, Pem2 in 32-t chunks =================
    const int p = blockIdx.x - NCONS;      // j-quad p -> emis rows 4p..4p+3
    const int j0 = p * 4;

    // ptot = sum exp(prior)
    float e = (tid < Nn) ? __expf(prior[tid]) : 0.f;
    ss[tid] = e; __syncthreads();
    for (int off = 512; off; off >>= 1) { if (tid < off) ss[tid] += ss[tid + off]; __syncthreads(); }
    const float ptot = ss[0];

    // single-pass interleaved row-sums for the 4 rows
    const f4* q0 = (const f4*)(emis + (size_t)(j0 + 0) * Mm);
    const f4* q1 = (const f4*)(emis + (size_t)(j0 + 1) * Mm);
    const f4* q2 = (const f4*)(emis + (size_t)(j0 + 2) * Mm);
    const f4* q3 = (const f4*)(emis + (size_t)(j0 + 3) * Mm);
    f4 a4 = {0.f, 0.f, 0.f, 0.f};
    for (int i = tid; i < Mm / 4; i += 1024) {
      f4 v0 = q0[i], v1 = q1[i], v2 = q2[i], v3 = q3[i];
      a4[0] += (__expf(v0[0]) + __expf(v0[1])) + (__expf(v0[2]) + __expf(v0[3]));
      a4[1] += (__expf(v1[0]) + __expf(v1[1])) + (__expf(v1[2]) + __expf(v1[3]));
      a4[2] += (__expf(v2[0]) + __expf(v2[1])) + (__expf(v2[2]) + __expf(v2[3]));
      a4[3] += (__expf(v3[0]) + __expf(v3[1])) + (__expf(v3[2]) + __expf(v3[3]));
    }
    ss4[tid] = a4; __syncthreads();
    for (int off = 512; off; off >>= 1) { if (tid < off) ss4[tid] += ss4[tid + off]; __syncthreads(); }
    f4 tot = ss4[0];
    f4 rs, fz;
    #pragma unroll
    for (int q = 0; q < 4; ++q) {
      rs[q] = 32768.f / tot[q];                               // 2^15 scale
      fz[q] = rs[q] * 256.f * __expf(prior[j0 + q]) / ptot;   // t=0: * 2^8 * pi
    }

    // gather + publish in 32-timestep chunks
    const float* r0 = emis + (size_t)(j0 + 0) * Mm;
    const float* r1 = emis + (size_t)(j0 + 1) * Mm;
    const float* r2 = emis + (size_t)(j0 + 2) * Mm;
    const float* r3 = emis + (size_t)(j0 + 3) * Mm;
    f4* P4 = (f4*)Pem2;
    for (int c8 = 0; c8 < 8; ++c8) {
      #pragma unroll
      for (int r = 0; r < 2; ++r) {
        int idx = c8 * 2048 + r * 1024 + tid;
        int t = idx >> 6, b = idx & 63;
        int mv = x[b * Tt + t];
        f4 fq = (t == 0) ? fz : rs;
        f4 o = { __expf(r0[mv]) * fq[0], __expf(r1[mv]) * fq[1],
                 __expf(r2[mv]) * fq[2], __expf(r3[mv]) * fq[3] };
        P4[t * 8192 + (b >> 4) * 2048 + p * 16 + (b & 15)] = o;
      }
      __syncthreads();
      if (tid == 0) {
        __builtin_amdgcn_fence(__ATOMIC_RELEASE, "agent");
        __hip_atomic_fetch_add(&progress[c8], 1, __ATOMIC_RELAXED, __HIP_MEMORY_SCOPE_AGENT);
      }
    }
    return;
  }

  // ================= consumer: 16 waves, 32 A-rows each =================
  const int g = blockIdx.x;
  const int w = tid >> 6, lane = tid & 63;
  const int c = lane & 15, kq = lane >> 4;
  const int jw = w * 32;                    // this wave's 32 A-rows
  const int swz = (c & 7) << 4;
  const int b = g * 16 + c;

  // A fragments (one-time): lane holds A_s[jw+rt*16+c][kc*128+kq*32 .. +31]  (64 regs)
  v8i af[2][4];
  #pragma unroll
  for (int rt = 0; rt < 2; ++rt)
    #pragma unroll
    for (int kc = 0; kc < 4; ++kc)
      af[rt][kc] = *reinterpret_cast<const v8i*>(
          A8 + (size_t)(jw + rt * 16 + c) * Nn + kc * 128 + kq * 32);

  // AGPR launder (binding verified r13): af lives in the accumulator class,
  // VGPR working set (~60) + af (64 AGPR) = 124 <= 128 budget at 4 waves/EU.
  #pragma unroll
  for (int rt = 0; rt < 2; ++rt)
    #pragma unroll
    for (int kc = 0; kc < 4; ++kc)
      asm volatile("" : "+a"(af[rt][kc]));

  const int Tb = Tlen[b];
  int E = 23;                               // Y = 2^E * alpha
  int csafe = 0;

  #define ENSURE(NEED)                                                                      \
    while (csafe <= (NEED)) {                                                               \
      if (__hip_atomic_load(&progress[csafe], __ATOMIC_RELAXED,                             \
                            __HIP_MEMORY_SCOPE_AGENT) >= NPROD) {                           \
        ++csafe;                                                                            \
        __builtin_amdgcn_fence(__ATOMIC_ACQUIRE, "agent");                                  \
      } else __builtin_amdgcn_s_sleep(2);                                                   \
    }

  // LDS byte offsets (XOR identities: kc*128 = bits>=7 disjoint from swz)
  const int roA0 = (c * Nn + kq * 32) ^ swz;        // + kc*128, ^16 for hi half
  const int roB0 = roA0 ^ 16;
  const int wof0 = (c * Nn + jw + kq * 4) ^ swz;    // ^16 for rt=1
  const int wof1 = wof0 ^ 16;
  char* const yb0 = &ybuf[0][0];

  if (tid < 640) ((float*)&Spart[0][0][0])[tid] = 0.f;
  __syncthreads();

  ENSURE(0);                                // Pem2 chunk 0 ready

  // init: Y0 = Pem2[0] (includes 2^23 * pi * emprob); 1024 threads, 8 rows each
  {
    int cc = tid & 15, grp = tid >> 4, jb = grp * 8, sz = (cc & 7) << 4;
    const f4* P0 = (const f4*)Pem2 + g * 2048 + (jb >> 2) * 16 + cc;
    float psum = 0.f;
    #pragma unroll
    for (int q = 0; q < 2; ++q) {
      f4 v = P0[q * 16];
      psum += (v[0] + v[1]) + (v[2] + v[3]);
      *reinterpret_cast<int*>(yb0 + ((cc * Nn + jb + q * 4) ^ sz)) = pk4fp8(v[0], v[1], v[2], v[3]);
    }
    atomicAdd(&Spart[0][cc][grp & 7], psum);
  }
  __syncthreads();

  const f4* PB = (const f4*)Pem2;
  #define PIDX(T, RT) ((T) * 8192 + g * 2048 + ((jw + (RT) * 16) >> 2) * 16 + kq * 16 + c)

  int pp = 0;                               // LDS buffer byte toggle (0/8192)
  for (int t = 1; t <= Tt; ++t) {
    // chunk-wait ONLY for t < Tt (t==Tt would wait on nonexistent chunk 8 -> deadlock)
    if (t < Tt && (t & 31) == 0) ENSURE(t >> 5);

    // emission probs for CURRENT t (latency hidden under MFMA phase)
    f4 pem0, pem1;
    if (t < Tt) { pem0 = PB[PIDX(t, 0)]; pem1 = PB[PIDX(t, 1)]; }

    int sp = pp >> 13;
    f4 s0 = *reinterpret_cast<const f4*>(&Spart[sp][c][0]);
    f4 s1 = *reinterpret_cast<const f4*>(&Spart[sp][c][4]);
    f4 s2 = *reinterpret_cast<const f4*>(&Spart[sp][c][8]);
    f4 s3 = *reinterpret_cast<const f4*>(&Spart[sp][c][12]);
    f4 st = (s0 + s1) + (s2 + s3);
    float S = (st[0] + st[1]) + (st[2] + st[3]);
    int expb = (int)((__float_as_uint(S) >> 23) & 0xFF);
    if (w == 0 && kq == 0 && Tb == t) out[b] = __logf(S) - (float)E * 0.69314718056f;
    if (t == Tt) break;
    E += 150 - expb;                        // E += 23 - ilogb(S)
    float scl = __uint_as_float((unsigned)(254 - expb) << 23);   // 2^-ilogb(S)

    // B fragments streamed 2-at-a-time; 8 MFMAs total per wave
    const char* rp = yb0 + pp;
    v4f a0 = {0.f,0.f,0.f,0.f}, a1 = {0.f,0.f,0.f,0.f};
    union BU { v8i v; v4i h[2]; };
    BU bu0, bu1;
    bu0.h[0] = *reinterpret_cast<const v4i*>(rp + roA0);
    bu0.h[1] = *reinterpret_cast<const v4i*>(rp + roB0);
    bu1.h[0] = *reinterpret_cast<const v4i*>(rp + roA0 + 128);
    bu1.h[1] = *reinterpret_cast<const v4i*>(rp + roB0 + 128);
    a0 = __builtin_amdgcn_mfma_scale_f32_16x16x128_f8f6f4(af[0][0], bu0.v, a0, 0, 0, 0, 0x7F, 0, 0x7F);
    a1 = __builtin_amdgcn_mfma_scale_f32_16x16x128_f8f6f4(af[1][0], bu0.v, a1, 0, 0, 0, 0x7F, 0, 0x7F);
    a0 = __builtin_amdgcn_mfma_scale_f32_16x16x128_f8f6f4(af[0][1], bu1.v, a0, 0, 0, 0, 0x7F, 0, 0x7F);
    a1 = __builtin_amdgcn_mfma_scale_f32_16x16x128_f8f6f4(af[1][1], bu1.v, a1, 0, 0, 0, 0x7F, 0, 0x7F);
    bu0.h[0] = *reinterpret_cast<const v4i*>(rp + roA0 + 256);
    bu0.h[1] = *reinterpret_cast<const v4i*>(rp + roB0 + 256);
    bu1.h[0] = *reinterpret_cast<const v4i*>(rp + roA0 + 384);
    bu1.h[1] = *reinterpret_cast<const v4i*>(rp + roB0 + 384);
    a0 = __builtin_amdgcn_mfma_scale_f32_16x16x128_f8f6f4(af[0][2], bu0.v, a0, 0, 0, 0, 0x7F, 0, 0x7F);
    a1 = __builtin_amdgcn_mfma_scale_f32_16x16x128_f8f6f4(af[1][2], bu0.v, a1, 0, 0, 0, 0x7F, 0, 0x7F);
    a0 = __builtin_amdgcn_mfma_scale_f32_16x16x128_f8f6f4(af[0][3], bu1.v, a0, 0, 0, 0, 0x7F, 0, 0x7F);
    a1 = __builtin_amdgcn_mfma_scale_f32_16x16x128_f8f6f4(af[1][3], bu1.v, a1, 0, 0, 0, 0x7F, 0, 0x7F);

    // epilogue: Y_t = acc .* pem .* 2^-e
    v4f scl4 = {scl, scl, scl, scl};
    char* wp = yb0 + (pp ^ 8192);
    v4f v0 = a0 * (pem0 * scl4);
    v4f v1 = a1 * (pem1 * scl4);
    *reinterpret_cast<int*>(wp + wof0) = pk4fp8(v0[0], v0[1], v0[2], v0[3]);
    *reinterpret_cast<int*>(wp + wof1) = pk4fp8(v1[0], v1[1], v1[2], v1[3]);
    f4 vs4 = v0 + v1;
    float vsum = (vs4[0] + vs4[1]) + (vs4[2] + vs4[3]);
    vsum += __shfl_xor(vsum, 16);
    vsum += __shfl_xor(vsum, 32);
    if (kq == 0) Spart[sp ^ 1][c][w] = vsum;

    pp ^= 8192;
    __syncthreads();
  }
  #undef PIDX
  #undef ENSURE
}

extern "C" void kernel_launch(void* const* d_in, const int* in_sizes, int n_in,
                              void* d_out, int out_size, void* d_ws, size_t ws_size,
                              hipStream_t stream) {
  const int*   x     = (const int*)  d_in[0];
  const int*   Tlen  = (const int*)  d_in[1];
  const float* trans = (const float*)d_in[2];
  const float* emis  = (const float*)d_in[3];
  const float* prior = (const float*)d_in[4];
  float* out = (float*)d_out;

  char* w = (char*)d_ws;
  char*  A8       = (char*)(w);                        // 256 KB fp8 A_s[j][k]
  float* colsum   = (float*)(w + (512 << 10));         // 2 KB
  int*   progress = (int*)  (w + (512 << 10) + 4096);  // 8 chunk counters
  float* Pem2     = (float*)(w + (1024 << 10));        // 32 MB Pem2[t][g][j>>2][c][j&3]

  hipMemsetAsync(w + (512 << 10), 0, 8192, stream);    // colsum + progress
  k_colsum <<<32,  256, 0, stream>>>(trans, colsum);
  k_writeA8<<<256, 256, 0, stream>>>(trans, colsum, (int*)A8);
  k_fused  <<<NCONS + NPROD, 1024, 0, stream>>>(A8, emis, x, prior, Tlen, Pem2, progress, out);
}

// Round 16
// 297.637 us; speedup vs baseline: 1.1436x; 1.1436x over previous
//
#include <hip/hip_runtime.h>
#include <math.h>

#define Nn 512
#define Mm 32000
#define Bb 64
#define Tt 256
#define NCONS 4     // consumer (recursion) blocks, 512 threads / 8 waves each
#define NPROD 128   // producer (emission) blocks

typedef float v4f __attribute__((ext_vector_type(4)));
typedef float f4  __attribute__((ext_vector_type(4)));
typedef int   v4i __attribute__((ext_vector_type(4)));
typedef int   v8i __attribute__((ext_vector_type(8)));

// pack 4 f32 -> 4 OCP e4m3 bytes in an int
__device__ inline int pk4fp8(float a, float b, float c, float d) {
  int r = __builtin_amdgcn_cvt_pk_fp8_f32(a, b, 0, false);
  r = __builtin_amdgcn_cvt_pk_fp8_f32(c, d, r, true);
  return r;
}

// ---- colsum[k] = sum_j exp(trans[j][k]) ----
__global__ void k_colsum(const float* __restrict__ trans, float* __restrict__ colsum) {
  int tid = threadIdx.x;
  int j0 = blockIdx.x * 16;
  float a0 = 0.f, a1 = 0.f;
  for (int r = 0; r < 16; ++r) {
    a0 += __expf(trans[(j0 + r) * Nn + tid]);
    a1 += __expf(trans[(j0 + r) * Nn + 256 + tid]);
  }
  atomicAdd(&colsum[tid], a0);
  atomicAdd(&colsum[256 + tid], a1);
}

// ---- A_s[j][k] = 256*exp(trans[j][k])/colsum[k] as e4m3 ----
__global__ void k_writeA8(const float* __restrict__ trans, const float* __restrict__ colsum,
                          int* __restrict__ A8) {
  int d = blockIdx.x * 256 + threadIdx.x;
  int j = d >> 7, k0 = (d & 127) << 2;
  float v0 = 256.f * __expf(trans[j * Nn + k0 + 0]) / colsum[k0 + 0];
  float v1 = 256.f * __expf(trans[j * Nn + k0 + 1]) / colsum[k0 + 1];
  float v2 = 256.f * __expf(trans[j * Nn + k0 + 2]) / colsum[k0 + 2];
  float v3 = 256.f * __expf(trans[j * Nn + k0 + 3]) / colsum[k0 + 3];
  A8[d] = pk4fp8(v0, v1, v2, v3);
}

// ---- fused: blocks 0-3 recursion consumers (8 waves, 64 A-rows/wave), 4-131 producers ----
// r12 base + VALU diet (unroll x2, static parity, pointer-inc pem, precomputed addrs).
// r15 bugfixes: (1) LDS write offsets must be XOR (wf0^rt*16), NOT add — post-swizzle
// wf0 has bits 4-5 set for odd c, ADD carried into wrong slots -> stale LDS -> e4m3
// NaN patterns -> NaN cascade. (2) pem timestep stride is 8192 f4 (not 2048):
// even step reads pemP+8192, pair increment is 16384.
__global__ __attribute__((amdgpu_flat_work_group_size(512, 512), amdgpu_waves_per_eu(2, 2)))
void k_fused(
    const char* __restrict__ A8, const float* __restrict__ emis,
    const int* __restrict__ x, const float* __restrict__ prior,
    const int* __restrict__ Tlen, float* __restrict__ Pem2,
    int* __restrict__ progress, float* __restrict__ out)
{
  __shared__ __align__(16) char ybuf[2][16 * Nn];   // fp8 Y [c][k], XOR-swizzled; 16 KB
  __shared__ __align__(16) float Spart[2][16][12];  // [c][w] column-sum partials (padded)
  __shared__ __align__(16) float ss[512];
  __shared__ __align__(16) f4 ss4[512];
  const int tid = threadIdx.x;

  if (blockIdx.x >= NCONS) {
    // ================= producer: 4 emis rows, Pem2 in 32-t chunks =================
    const int p = blockIdx.x - NCONS;      // j-quad p -> emis rows 4p..4p+3
    const int j0 = p * 4;

    // ptot = sum exp(prior)  (512 threads == Nn)
    float e = __expf(prior[tid]);
    ss[tid] = e; __syncthreads();
    for (int off = 256; off; off >>= 1) { if (tid < off) ss[tid] += ss[tid + off]; __syncthreads(); }
    const float ptot = ss[0];

    // single-pass interleaved row-sums for the 4 rows
    const f4* q0 = (const f4*)(emis + (size_t)(j0 + 0) * Mm);
    const f4* q1 = (const f4*)(emis + (size_t)(j0 + 1) * Mm);
    const f4* q2 = (const f4*)(emis + (size_t)(j0 + 2) * Mm);
    const f4* q3 = (const f4*)(emis + (size_t)(j0 + 3) * Mm);
    f4 a4 = {0.f, 0.f, 0.f, 0.f};
    for (int i = tid; i < Mm / 4; i += 512) {
      f4 v0 = q0[i], v1 = q1[i], v2 = q2[i], v3 = q3[i];
      a4[0] += (__expf(v0[0]) + __expf(v0[1])) + (__expf(v0[2]) + __expf(v0[3]));
      a4[1] += (__expf(v1[0]) + __expf(v1[1])) + (__expf(v1[2]) + __expf(v1[3]));
      a4[2] += (__expf(v2[0]) + __expf(v2[1])) + (__expf(v2[2]) + __expf(v2[3]));
      a4[3] += (__expf(v3[0]) + __expf(v3[1])) + (__expf(v3[2]) + __expf(v3[3]));
    }
    ss4[tid] = a4; __syncthreads();
    for (int off = 256; off; off >>= 1) { if (tid < off) ss4[tid] += ss4[tid + off]; __syncthreads(); }
    f4 tot = ss4[0];
    f4 rs, fz;
    #pragma unroll
    for (int q = 0; q < 4; ++q) {
      rs[q] = 32768.f / tot[q];                               // 2^15 scale
      fz[q] = rs[q] * 256.f * __expf(prior[j0 + q]) / ptot;   // t=0: * 2^8 * pi
    }

    // gather + publish in 32-timestep chunks
    const float* r0 = emis + (size_t)(j0 + 0) * Mm;
    const float* r1 = emis + (size_t)(j0 + 1) * Mm;
    const float* r2 = emis + (size_t)(j0 + 2) * Mm;
    const float* r3 = emis + (size_t)(j0 + 3) * Mm;
    f4* P4 = (f4*)Pem2;
    for (int c8 = 0; c8 < 8; ++c8) {
      #pragma unroll
      for (int r = 0; r < 4; ++r) {
        int idx = c8 * 2048 + r * 512 + tid;
        int t = idx >> 6, b = idx & 63;
        int mv = x[b * Tt + t];
        f4 fq = (t == 0) ? fz : rs;
        f4 o = { __expf(r0[mv]) * fq[0], __expf(r1[mv]) * fq[1],
                 __expf(r2[mv]) * fq[2], __expf(r3[mv]) * fq[3] };
        P4[t * 8192 + (b >> 4) * 2048 + p * 16 + (b & 15)] = o;
      }
      __syncthreads();
      if (tid == 0) {
        __builtin_amdgcn_fence(__ATOMIC_RELEASE, "agent");
        __hip_atomic_fetch_add(&progress[c8], 1, __ATOMIC_RELAXED, __HIP_MEMORY_SCOPE_AGENT);
      }
    }
    return;
  }

  // ================= consumer: 8 waves, 64 A-rows each =================
  const int g = blockIdx.x;
  const int w = tid >> 6, lane = tid & 63;
  const int c = lane & 15, kq = lane >> 4;
  const int jw = w * 64;                    // this wave's 64 A-rows
  const int swz = (c & 7) << 4;
  const int b = g * 16 + c;

  // A fragments (one-time): lane holds A_s[jw+rt*16+c][kc*128+kq*32 .. +31]  (128 regs)
  v8i af[4][4];
  #pragma unroll
  for (int rt = 0; rt < 4; ++rt)
    #pragma unroll
    for (int kc = 0; kc < 4; ++kc)
      af[rt][kc] = *reinterpret_cast<const v8i*>(
          A8 + (size_t)(jw + rt * 16 + c) * Nn + kc * 128 + kq * 32);

  // launder: block rematerialization/sinking of the af loads into the loop
  #pragma unroll
  for (int rt = 0; rt < 4; ++rt)
    #pragma unroll
    for (int kc = 0; kc < 4; ++kc)
      asm volatile("" : "+v"(af[rt][kc]));

  const int Tb = Tlen[b];
  int E = 23;                               // Y = 2^E * alpha
  int csafe = 0;

  #define ENSURE(NEED)                                                                      \
    while (csafe <= (NEED)) {                                                               \
      if (__hip_atomic_load(&progress[csafe], __ATOMIC_RELAXED,                             \
                            __HIP_MEMORY_SCOPE_AGENT) >= NPROD) {                           \
        ++csafe;                                                                            \
        __builtin_amdgcn_fence(__ATOMIC_ACQUIRE, "agent");                                  \
      } else __builtin_amdgcn_s_sleep(2);                                                   \
    }

  // LDS byte offsets. Write offsets use XOR (wf_rt = wf0 ^ rt*16 — exact since the
  // pre-swizzle base has bits 4,5 = 0); reads add kc*128 (bits 7,8 of roA0 are 0).
  const int roA0 = (c * Nn + kq * 32) ^ swz;
  const int roB0 = roA0 ^ 16;
  const int wf0 = (c * Nn + jw + kq * 4) ^ swz;
  const int wf1 = wf0 ^ 16, wf2 = wf0 ^ 32, wf3 = wf0 ^ 48;
  char* const yb0 = &ybuf[0][0];

  // precomputed loop-invariant bases (odd step: read buf0 -> write buf1)
  const char* rdA_e = yb0 + roA0;          // odd-step read bases (buf0)
  const char* rdB_e = yb0 + roB0;
  const char* rdA_o = rdA_e + 8192;        // even-step read bases (buf1)
  const char* rdB_o = rdB_e + 8192;
  char* const wb_o = yb0 + 8192;           // odd-step write base (buf1)
  char* const wb_e = yb0;                  // even-step write base (buf0)
  const float* sprd0 = &Spart[0][c][0];
  const float* sprd1 = &Spart[1][c][0];
  float* spwr0 = &Spart[1][c][w];          // odd step writes Spart[1]
  float* spwr1 = &Spart[0][c][w];          // even step writes Spart[0]

  if (tid < 192) ((float*)&Spart[0][0][0])[tid] = 0.f;
  __syncthreads();

  ENSURE(0);                                // Pem2 chunk 0 ready

  // init: Y0 = Pem2[0] (includes 2^23 * pi * emprob); 512 threads, 16 rows each
  {
    int cc = tid & 15, grp = tid >> 4, jb = grp * 16, sz = (cc & 7) << 4;
    const f4* P0 = (const f4*)Pem2 + g * 2048 + (jb >> 2) * 16 + cc;
    float psum = 0.f;
    #pragma unroll
    for (int q = 0; q < 4; ++q) {
      f4 v = P0[q * 16];
      psum += (v[0] + v[1]) + (v[2] + v[3]);
      *reinterpret_cast<int*>(yb0 + ((cc * Nn + jb + q * 4) ^ sz)) = pk4fp8(v[0], v[1], v[2], v[3]);
    }
    atomicAdd(&Spart[0][cc][grp & 7], psum);
  }
  __syncthreads();

  // pem pointer: PIDX(1,0) = 8192 + g*2048 + jw*4 + kq*16 + c (f4 units);
  // RT stride 64 f4 (imm offsets); timestep stride 8192 f4.
  const f4* pemP = (const f4*)Pem2 + (8192 + g * 2048 + jw * 4 + kq * 16 + c);

  union BU { v8i v; v4i h[2]; };

  #define MFMA16(RDA, RDB)                                                                   \
    {                                                                                        \
      BU bu0, bu1;                                                                           \
      bu0.h[0] = *(const v4i*)((RDA) + 0);   bu0.h[1] = *(const v4i*)((RDB) + 0);            \
      bu1.h[0] = *(const v4i*)((RDA) + 128); bu1.h[1] = *(const v4i*)((RDB) + 128);          \
      a0 = __builtin_amdgcn_mfma_scale_f32_16x16x128_f8f6f4(af[0][0], bu0.v, a0, 0,0,0, 0x7F, 0, 0x7F); \
      a1 = __builtin_amdgcn_mfma_scale_f32_16x16x128_f8f6f4(af[1][0], bu0.v, a1, 0,0,0, 0x7F, 0, 0x7F); \
      a2 = __builtin_amdgcn_mfma_scale_f32_16x16x128_f8f6f4(af[2][0], bu0.v, a2, 0,0,0, 0x7F, 0, 0x7F); \
      a3 = __builtin_amdgcn_mfma_scale_f32_16x16x128_f8f6f4(af[3][0], bu0.v, a3, 0,0,0, 0x7F, 0, 0x7F); \
      a0 = __builtin_amdgcn_mfma_scale_f32_16x16x128_f8f6f4(af[0][1], bu1.v, a0, 0,0,0, 0x7F, 0, 0x7F); \
      a1 = __builtin_amdgcn_mfma_scale_f32_16x16x128_f8f6f4(af[1][1], bu1.v, a1, 0,0,0, 0x7F, 0, 0x7F); \
      a2 = __builtin_amdgcn_mfma_scale_f32_16x16x128_f8f6f4(af[2][1], bu1.v, a2, 0,0,0, 0x7F, 0, 0x7F); \
      a3 = __builtin_amdgcn_mfma_scale_f32_16x16x128_f8f6f4(af[3][1], bu1.v, a3, 0,0,0, 0x7F, 0, 0x7F); \
      bu0.h[0] = *(const v4i*)((RDA) + 256); bu0.h[1] = *(const v4i*)((RDB) + 256);          \
      bu1.h[0] = *(const v4i*)((RDA) + 384); bu1.h[1] = *(const v4i*)((RDB) + 384);          \
      a0 = __builtin_amdgcn_mfma_scale_f32_16x16x128_f8f6f4(af[0][2], bu0.v, a0, 0,0,0, 0x7F, 0, 0x7F); \
      a1 = __builtin_amdgcn_mfma_scale_f32_16x16x128_f8f6f4(af[1][2], bu0.v, a1, 0,0,0, 0x7F, 0, 0x7F); \
      a2 = __builtin_amdgcn_mfma_scale_f32_16x16x128_f8f6f4(af[2][2], bu0.v, a2, 0,0,0, 0x7F, 0, 0x7F); \
      a3 = __builtin_amdgcn_mfma_scale_f32_16x16x128_f8f6f4(af[3][2], bu0.v, a3, 0,0,0, 0x7F, 0, 0x7F); \
      a0 = __builtin_amdgcn_mfma_scale_f32_16x16x128_f8f6f4(af[0][3], bu1.v, a0, 0,0,0, 0x7F, 0, 0x7F); \
      a1 = __builtin_amdgcn_mfma_scale_f32_16x16x128_f8f6f4(af[1][3], bu1.v, a1, 0,0,0, 0x7F, 0, 0x7F); \
      a2 = __builtin_amdgcn_mfma_scale_f32_16x16x128_f8f6f4(af[2][3], bu1.v, a2, 0,0,0, 0x7F, 0, 0x7F); \
      a3 = __builtin_amdgcn_mfma_scale_f32_16x16x128_f8f6f4(af[3][3], bu1.v, a3, 0,0,0, 0x7F, 0, 0x7F); \
    }

  #define EPILOG(WBASE, SPWP)                                                                \
    {                                                                                        \
      v4f scl4 = {scl, scl, scl, scl};                                                       \
      v4f v0 = a0 * (pem0 * scl4);                                                           \
      v4f v1 = a1 * (pem1 * scl4);                                                           \
      v4f v2 = a2 * (pem2 * scl4);                                                           \
      v4f v3 = a3 * (pem3 * scl4);                                                           \
      *(int*)((WBASE) + wf0) = pk4fp8(v0[0], v0[1], v0[2], v0[3]);                           \
      *(int*)((WBASE) + wf1) = pk4fp8(v1[0], v1[1], v1[2], v1[3]);                           \
      *(int*)((WBASE) + wf2) = pk4fp8(v2[0], v2[1], v2[2], v2[3]);                           \
      *(int*)((WBASE) + wf3) = pk4fp8(v3[0], v3[1], v3[2], v3[3]);                           \
      f4 vs4 = (v0 + v1) + (v2 + v3);                                                        \
      float vsum = (vs4[0] + vs4[1]) + (vs4[2] + vs4[3]);                                    \
      vsum += __shfl_xor(vsum, 16);                                                          \
      vsum += __shfl_xor(vsum, 32);                                                          \
      if (kq == 0) *(SPWP) = vsum;                                                           \
    }

  for (int t = 1; t <= Tt; t += 2) {
    // ---------- ODD step t: read buf0 / Spart0, write buf1 / Spart1 ----------
    {
      f4 pem0 = pemP[0], pem1 = pemP[64], pem2 = pemP[128], pem3 = pemP[192];
      f4 s0 = *(const f4*)sprd0;
      f4 s1 = *(const f4*)(sprd0 + 4);
      f4 st = s0 + s1;
      float S = (st[0] + st[1]) + (st[2] + st[3]);
      int expb = (int)((__float_as_uint(S) >> 23) & 0xFF);
      if (w == 0 && kq == 0 && Tb == t) out[b] = __logf(S) - (float)E * 0.69314718056f;
      E += 150 - expb;
      float scl = __uint_as_float((unsigned)(254 - expb) << 23);

      v4f a0 = {0.f,0.f,0.f,0.f}, a1 = {0.f,0.f,0.f,0.f};
      v4f a2 = {0.f,0.f,0.f,0.f}, a3 = {0.f,0.f,0.f,0.f};
      MFMA16(rdA_e, rdB_e)
      EPILOG(wb_o, spwr0)
      __syncthreads();
    }
    // ---------- EVEN step t+1: read buf1 / Spart1, write buf0 / Spart0 ----------
    {
      const int T = t + 1;
      if (T < Tt && (T & 31) == 0) ENSURE(T >> 5);
      f4 pem0, pem1, pem2, pem3;
      const f4* p2 = pemP + 8192;          // next timestep (8192 f4 stride)
      if (T < Tt) { pem0 = p2[0]; pem1 = p2[64]; pem2 = p2[128]; pem3 = p2[192]; }
      f4 s0 = *(const f4*)sprd1;
      f4 s1 = *(const f4*)(sprd1 + 4);
      f4 st = s0 + s1;
      float S = (st[0] + st[1]) + (st[2] + st[3]);
      int expb = (int)((__float_as_uint(S) >> 23) & 0xFF);
      if (w == 0 && kq == 0 && Tb == T) out[b] = __logf(S) - (float)E * 0.69314718056f;
      if (T == Tt) goto done;
      E += 150 - expb;
      float scl = __uint_as_float((unsigned)(254 - expb) << 23);

      v4f a0 = {0.f,0.f,0.f,0.f}, a1 = {0.f,0.f,0.f,0.f};
      v4f a2 = {0.f,0.f,0.f,0.f}, a3 = {0.f,0.f,0.f,0.f};
      MFMA16(rdA_o, rdB_o)
      EPILOG(wb_e, spwr1)
      __syncthreads();
    }
    pemP += 16384;                          // two timesteps
  }
done: ;
  #undef MFMA16
  #undef EPILOG
  #undef ENSURE
}

extern "C" void kernel_launch(void* const* d_in, const int* in_sizes, int n_in,
                              void* d_out, int out_size, void* d_ws, size_t ws_size,
                              hipStream_t stream) {
  const int*   x     = (const int*)  d_in[0];
  const int*   Tlen  = (const int*)  d_in[1];
  const float* trans = (const float*)d_in[2];
  const float* emis  = (const float*)d_in[3];
  const float* prior = (const float*)d_in[4];
  float* out = (float*)d_out;

  char* w = (char*)d_ws;
  char*  A8       = (char*)(w);                        // 256 KB fp8 A_s[j][k]
  float* colsum   = (float*)(w + (512 << 10));         // 2 KB
  int*   progress = (int*)  (w + (512 << 10) + 4096);  // 8 chunk counters
  float* Pem2     = (float*)(w + (1024 << 10));        // 32 MB Pem2[t][g][j>>2][c][j&3]

  hipMemsetAsync(w + (512 << 10), 0, 8192, stream);    // colsum + progress
  k_colsum <<<32,  256, 0, stream>>>(trans, colsum);
  k_writeA8<<<256, 256, 0, stream>>>(trans, colsum, (int*)A8);
  k_fused  <<<NCONS + NPROD, 512, 0, stream>>>(A8, emis, x, prior, Tlen, Pem2, progress, out);
}